// Round 1
// baseline (24418.547 us; speedup 1.0000x reference)
//
#include <hip/hip_runtime.h>
#include <hip/hip_bf16.h>
#include <stdint.h>

// Problem dims
#define NB   128
#define NT   1024
#define NF   512
#define NH   512
#define G4   2048   // 4*H
#define NOUT 24
#define NWG  192    // persistent grid: 64 L1-rec + 64 XP2-proj + 64 L2-rec

typedef __attribute__((ext_vector_type(8))) short short8;
typedef __attribute__((ext_vector_type(4))) float f32x4;

__device__ __forceinline__ float bf2f(short s) {
  union { unsigned u; float f; } v; v.u = ((unsigned)(unsigned short)s) << 16; return v.f;
}
__device__ __forceinline__ short f2bf(float f) {
  union { float f; unsigned u; } v; v.f = f;
  unsigned r = v.u + 0x7FFF + ((v.u >> 16) & 1);   // RNE
  return (short)(r >> 16);
}
// permuted gate-column layout: cp = wg*32 + [i:0-7 | f:8-15 | g:16-23 | o:24-31]
__device__ __forceinline__ int permcol(int cp) {
  int w = cp >> 5, l = cp & 31;
  return ((l >> 3) << 9) | (w << 3) | (l & 7);   // gate*512 + w*8 + u
}
__device__ __forceinline__ float sigm(float x) { return 1.f / (1.f + __expf(-x)); }
__device__ __forceinline__ float tanh_f(float x) { return 2.f / (1.f + __expf(-2.f * x)) - 1.f; }

// ---------------- prep: W1^T (permuted cols, bf16) ----------------
__global__ void prep_w1t(const float* __restrict__ W1, short* __restrict__ w1t) {
  int gid = blockIdx.x * 256 + threadIdx.x;      // 2048*64
  int cp = gid >> 6, kc = gid & 63;
  int orig = permcol(cp);
  const float* sp = W1 + (size_t)(kc * 8) * G4 + orig;
  short8 v;
#pragma unroll
  for (int j = 0; j < 8; ++j) v[j] = f2bf(sp[(size_t)j * G4]);
  *(short8*)&w1t[((size_t)cp << 9) + (kc << 3)] = v;
}

// ---------------- prep: fold 3 heads + final into one [512,24] ----------------
__global__ void prep_wcomb(const float* __restrict__ Wh1, const float* __restrict__ Wh2,
                           const float* __restrict__ Wh3, const float* __restrict__ bh1,
                           const float* __restrict__ bh2, const float* __restrict__ bh3,
                           const float* __restrict__ Wf, const float* __restrict__ bfv,
                           float* __restrict__ wcomb, float* __restrict__ bcomb) {
  int gid = blockIdx.x * 256 + threadIdx.x;
  if (gid < 512 * NOUT) {
    int k = gid / NOUT, o = gid - k * NOUT;
    float a = 0.f;
#pragma unroll
    for (int j = 0; j < 24; ++j) {
      float w = (j < 8) ? Wh1[k * 8 + j] : (j < 16) ? Wh2[k * 8 + (j - 8)] : Wh3[k * 8 + (j - 16)];
      a += w * Wf[j * NOUT + o];
    }
    wcomb[gid] = a;
  }
  if (gid < NOUT) {
    float a = bfv[gid];
#pragma unroll
    for (int j = 0; j < 24; ++j) {
      float bb = (j < 8) ? bh1[j] : (j < 16) ? bh2[j - 8] : bh3[j - 16];
      a += bb * Wf[j * NOUT + gid];
    }
    bcomb[gid] = a;
  }
}

// ---------------- GEMM: xp1[t*128+b][cp] = bf16( x@W1 + b1 ), permuted cols ----------------
// 128x128 tile, BK=64, 4 waves (2x2), 16x16x32 bf16 MFMA. Reg-staged (compile-safe v1).
__launch_bounds__(256, 2)
__global__ void gemm_xp1(const float* __restrict__ x, const short* __restrict__ w1t,
                         const float* __restrict__ b1, short* __restrict__ xp1) {
  __shared__ __align__(16) short As[128 * 64];
  __shared__ __align__(16) short Bs[128 * 64];
  const int tid = threadIdx.x;
  const int lane = tid & 63, wv = tid >> 6;
  const int wr = wv >> 1, wc = wv & 1;
  const int lc = lane & 15, lq = lane >> 4;
  const int nt = blockIdx.x, tt = blockIdx.y;   // tile row-block == time index
  const int n0 = nt << 7;
  f32x4 acc[4][4] = {};

  for (int kt = 0; kt < 8; ++kt) {
    const int k0 = kt << 6;
#pragma unroll
    for (int it = 0; it < 4; ++it) {
      int id = it * 256 + tid;
      int row = id >> 3, ch = id & 7;
      // A: x[b=row][t=tt][k0+ch*8..], f32 -> bf16, swizzled LDS dest
      const float* sp = x + ((size_t)row * NT + tt) * NF + k0 + ch * 8;
      f32x4 a0 = *(const f32x4*)sp;
      f32x4 a1 = *(const f32x4*)(sp + 4);
      short8 v;
      v[0] = f2bf(a0[0]); v[1] = f2bf(a0[1]); v[2] = f2bf(a0[2]); v[3] = f2bf(a0[3]);
      v[4] = f2bf(a1[0]); v[5] = f2bf(a1[1]); v[6] = f2bf(a1[2]); v[7] = f2bf(a1[3]);
      *(short8*)&As[(row << 6) + ((ch ^ (row & 7)) << 3)] = v;
      // B: W1T row (n0+row), bf16 copy
      const short* bp = w1t + ((size_t)(n0 + row) << 9) + k0 + ch * 8;
      *(short8*)&Bs[(row << 6) + ((ch ^ (row & 7)) << 3)] = *(const short8*)bp;
    }
    __syncthreads();
#pragma unroll
    for (int ks = 0; ks < 2; ++ks) {
      short8 af[4], bb[4];
#pragma unroll
      for (int i = 0; i < 4; ++i) {
        int ar = wr * 64 + i * 16 + lc;
        int ac = ks * 4 + lq;
        af[i] = *(const short8*)&As[(ar << 6) + ((ac ^ (ar & 7)) << 3)];
        int br = wc * 64 + i * 16 + lc;
        bb[i] = *(const short8*)&Bs[(br << 6) + ((ac ^ (br & 7)) << 3)];
      }
#pragma unroll
      for (int i = 0; i < 4; ++i)
#pragma unroll
        for (int j = 0; j < 4; ++j)
          acc[i][j] = __builtin_amdgcn_mfma_f32_16x16x32_bf16(af[i], bb[j], acc[i][j], 0, 0, 0);
    }
    __syncthreads();
  }
  const size_t m0 = (size_t)tt << 7;
#pragma unroll
  for (int j = 0; j < 4; ++j) {
    int cp = n0 + wc * 64 + j * 16 + lc;
    float bv = b1[permcol(cp)];
#pragma unroll
    for (int i = 0; i < 4; ++i) {
      int rbase = wr * 64 + i * 16 + lq * 4;
#pragma unroll
      for (int r = 0; r < 4; ++r)
        xp1[(m0 + rbase + r) * G4 + cp] = f2bf(acc[i][j][r] + bv);
    }
  }
}

// ---------------- persistent pipelined LSTM ----------------
// interval s: role0 computes h1[s]; role1 computes xp2[s-1]=h1[s-1]@W2+b2; role2 computes h2[s-2].
// U/W column slices live in registers (bfr). h exchanged via ping-pong global buffers,
// coherence by RELEASE(wbl2)/ACQUIRE(inv) on the barrier atomics (compiler-lowered).
__launch_bounds__(256, 1)
__global__ void lstm_persist(const float* __restrict__ U1, const float* __restrict__ W2,
                             const float* __restrict__ U2, const float* __restrict__ b2,
                             const short* __restrict__ xp1,
                             short* __restrict__ h1buf, short* __restrict__ h2buf,
                             short* __restrict__ xp2buf, short* __restrict__ h2all,
                             int* __restrict__ bar) {
  __shared__ __align__(16) short hs[128 * 256];   // 64 KB half-K staging
  const int bid = blockIdx.x;
  const int role = bid >> 6;    // 0:L1rec 1:XP2 2:L2rec
  const int wgc = bid & 63;     // 32-col group (8 h-units)
  const int tid = threadIdx.x;
  const int lane = tid & 63, wv = tid >> 6;
  const int lc = lane & 15, lq = lane >> 4;
  const bool fl = lc >= 8;      // f/o lanes (hold c-state, produce h)

  const float* Bmat = (role == 0) ? U1 : (role == 1) ? W2 : U2;

  // one-time: gather B fragments into registers (2 col-tiles x 16 k-steps)
  short8 bfr[2][16];
#pragma unroll
  for (int ct = 0; ct < 2; ++ct) {
    int cloc = ct * 16 + lc;
    int orig = ((cloc >> 3) << 9) | (wgc << 3) | (cloc & 7);
#pragma unroll
    for (int ks = 0; ks < 16; ++ks) {
      const float* up = Bmat + (size_t)(ks * 32 + lq * 8) * G4 + orig;
      short8 v;
#pragma unroll
      for (int jj = 0; jj < 8; ++jj) v[jj] = f2bf(up[(size_t)jj * G4]);
      bfr[ct][ks] = v;
    }
  }
  float bias2[2] = {0.f, 0.f};
  if (role == 1) {
#pragma unroll
    for (int ct = 0; ct < 2; ++ct) {
      int cloc = ct * 16 + lc;
      bias2[ct] = b2[((cloc >> 3) << 9) | (wgc << 3) | (cloc & 7)];
    }
  }
  float cst[2][4] = {};   // c-state (valid in f-lanes)

  for (int s = 0; s < NT + 2; ++s) {
    if (s) {
      __syncthreads();   // all waves' stores issued+drained (vmcnt0 before s_barrier)
      if (tid == 0) {
        __hip_atomic_fetch_add(bar, 1, __ATOMIC_RELEASE, __HIP_MEMORY_SCOPE_AGENT);
        const int target = NWG * s;
        while (__hip_atomic_load(bar, __ATOMIC_RELAXED, __HIP_MEMORY_SCOPE_AGENT) < target)
          __builtin_amdgcn_s_sleep(1);
        (void)__hip_atomic_load(bar, __ATOMIC_ACQUIRE, __HIP_MEMORY_SCOPE_AGENT);
      }
      __syncthreads();
    }
    int tau; bool active;
    if (role == 0)      { tau = s;     active = (s <= NT - 1); }
    else if (role == 1) { tau = s - 1; active = (s >= 1 && s <= NT); }
    else                { tau = s - 2; active = (s >= 2); }
    if (!active) continue;

    // acc init: role0 <- xp1 slice; role2 <- xp2 slice; role1 <- 0
    f32x4 acc[2][2] = {};
    if (role == 0) {
#pragma unroll
      for (int i = 0; i < 2; ++i)
#pragma unroll
        for (int j = 0; j < 2; ++j) {
          int col = (wgc << 5) + j * 16 + lc;
#pragma unroll
          for (int r = 0; r < 4; ++r) {
            int row = (wv << 5) + i * 16 + lq * 4 + r;
            acc[i][j][r] = bf2f(xp1[((size_t)(tau << 7) + row) * G4 + col]);
          }
        }
    } else if (role == 2) {
      const short* xs = xp2buf + (size_t)(tau & 1) * NB * G4;
#pragma unroll
      for (int i = 0; i < 2; ++i)
#pragma unroll
        for (int j = 0; j < 2; ++j) {
          int col = (wgc << 5) + j * 16 + lc;
#pragma unroll
          for (int r = 0; r < 4; ++r) {
            int row = (wv << 5) + i * 16 + lq * 4 + r;
            acc[i][j][r] = bf2f(xs[(size_t)row * G4 + col]);
          }
        }
    }

    // recurrent matmul vs staged h (all roles read parity (s-1)&1)
    const bool do_mm = (role == 0) ? (s > 0) : (role == 1) ? true : (tau > 0);
    if (do_mm) {
      const short* hsrc = (role == 2) ? (h2buf + (size_t)((s - 1) & 1) * NB * NH)
                                      : (h1buf + (size_t)((s - 1) & 1) * NB * NH);
#pragma unroll
      for (int hf = 0; hf < 2; ++hf) {
        __syncthreads();
#pragma unroll
        for (int it = 0; it < 16; ++it) {
          int id = it * 256 + tid;
          int row = id >> 5, ch = id & 31;
          short8 v = *(const short8*)(hsrc + (size_t)(row << 9) + (hf << 8) + (ch << 3));
          *(short8*)&hs[(row << 8) + ((ch ^ (row & 15)) << 3)] = v;
        }
        __syncthreads();
#pragma unroll
        for (int ks = 0; ks < 8; ++ks) {
          short8 af[2];
#pragma unroll
          for (int i = 0; i < 2; ++i) {
            int row = (wv << 5) + i * 16 + lc;
            int ch = ks * 4 + lq;
            af[i] = *(const short8*)&hs[(row << 8) + ((ch ^ (row & 15)) << 3)];
          }
#pragma unroll
          for (int i = 0; i < 2; ++i)
#pragma unroll
            for (int j = 0; j < 2; ++j)
              acc[i][j] = __builtin_amdgcn_mfma_f32_16x16x32_bf16(af[i], bfr[j][hf * 8 + ks],
                                                                  acc[i][j], 0, 0, 0);
        }
      }
    }

    if (role == 1) {
      short* xd = xp2buf + (size_t)(tau & 1) * NB * G4;
#pragma unroll
      for (int i = 0; i < 2; ++i)
#pragma unroll
        for (int j = 0; j < 2; ++j) {
          int col = (wgc << 5) + j * 16 + lc;
#pragma unroll
          for (int r = 0; r < 4; ++r) {
            int row = (wv << 5) + i * 16 + lq * 4 + r;
            xd[(size_t)row * G4 + col] = f2bf(acc[i][j][r] + bias2[j]);
          }
        }
    } else {
      // gates: acc[i][0] = z_i (c<8) / z_f (c>=8); acc[i][1] = z_g / z_o
      float hv[2][4];
#pragma unroll
      for (int i = 0; i < 2; ++i)
#pragma unroll
        for (int r = 0; r < 4; ++r) {
          float z0 = acc[i][0][r], z1 = acc[i][1][r];
          float s0 = sigm(z0);                 // i-gate (i-lanes) or f-gate (f-lanes)
          float pv = s0 * tanh_f(z1);          // i*tanh(g), valid on i-lanes
          float ov = sigm(z1);                 // o-gate, valid on f-lanes
          float pr = __shfl_xor(pv, 8);
          if (fl) {
            float cn = s0 * cst[i][r] + pr;
            cst[i][r] = cn;
            hv[i][r] = ov * tanh_f(cn);
          }
        }
      short* hb = (role == 0) ? (h1buf + (size_t)(s & 1) * NB * NH)
                              : (h2buf + (size_t)(s & 1) * NB * NH);
      if (fl) {
        int u = lc - 8;
#pragma unroll
        for (int i = 0; i < 2; ++i)
#pragma unroll
          for (int r = 0; r < 4; ++r) {
            int row = (wv << 5) + i * 16 + lq * 4 + r;
            short hbv = f2bf(hv[i][r]);
            hb[(size_t)(row << 9) + (wgc << 3) + u] = hbv;
            if (role == 2) h2all[((size_t)tau * NB + row) * NH + (wgc << 3) + u] = hbv;
          }
      }
    }
  }
}

// ---------------- heads: out = h2 @ Wcomb + bcomb, scattered to [B][T][24] ----------------
__launch_bounds__(192)
__global__ void heads_k(const short* __restrict__ h2all, const float* __restrict__ wcomb,
                        const float* __restrict__ bcomb, float* __restrict__ out) {
  __shared__ float wt[24][516];
  __shared__ float bsh[24];
  const int tid = threadIdx.x;
  for (int id = tid; id < 512 * NOUT; id += 192) {
    int k = id / NOUT, o = id - k * NOUT;
    wt[o][k] = wcomb[id];
  }
  if (tid < NOUT) bsh[tid] = bcomb[tid];
  __syncthreads();
  const int r = tid / NOUT, c = tid - r * NOUT;
  const size_t row = (size_t)blockIdx.x * 8 + r;   // row = t*128 + b
  const short* hp = h2all + row * NH;
  float a = bsh[c];
#pragma unroll 2
  for (int kc = 0; kc < 64; ++kc) {
    short8 hvv = *(const short8*)&hp[kc * 8];
    const float* wp = &wt[c][kc * 8];
#pragma unroll
    for (int e = 0; e < 8; ++e) a += bf2f(hvv[e]) * wp[e];
  }
  const int b = (int)(row & 127), t = (int)(row >> 7);
  out[((size_t)b * NT + t) * NOUT + c] = a;
}

// ---------------- launcher ----------------
extern "C" void kernel_launch(void* const* d_in, const int* in_sizes, int n_in,
                              void* d_out, int out_size, void* d_ws, size_t ws_size,
                              hipStream_t stream) {
  const float* x   = (const float*)d_in[0];
  const float* W1  = (const float*)d_in[1];
  const float* U1  = (const float*)d_in[2];
  const float* b1  = (const float*)d_in[3];
  const float* W2  = (const float*)d_in[4];
  const float* U2  = (const float*)d_in[5];
  const float* b2  = (const float*)d_in[6];
  const float* Wh1 = (const float*)d_in[7];
  const float* bh1 = (const float*)d_in[8];
  const float* Wh2 = (const float*)d_in[9];
  const float* bh2 = (const float*)d_in[10];
  const float* Wh3 = (const float*)d_in[11];
  const float* bh3 = (const float*)d_in[12];
  const float* Wf  = (const float*)d_in[13];
  const float* bfv = (const float*)d_in[14];
  float* out = (float*)d_out;

  char* ws = (char*)d_ws;
  size_t off = 0;
  auto alloc = [&](size_t bytes) { char* p = ws + off; off += (bytes + 255) & ~(size_t)255; return p; };
  int*   bar    = (int*)  alloc(256);
  short* xp1    = (short*)alloc((size_t)NT * NB * G4 * 2);   // 536 MB
  short* h2all  = (short*)alloc((size_t)NT * NB * NH * 2);   // 134 MB
  short* h1buf  = (short*)alloc((size_t)2 * NB * NH * 2);
  short* h2buf  = (short*)alloc((size_t)2 * NB * NH * 2);
  short* xp2buf = (short*)alloc((size_t)2 * NB * G4 * 2);
  short* w1t    = (short*)alloc((size_t)G4 * NF * 2);
  float* wcomb  = (float*)alloc(512 * NOUT * 4);
  float* bcomb  = (float*)alloc(256);
  (void)ws_size; (void)in_sizes; (void)n_in; (void)out_size;  // needs ~675 MB of ws

  hipMemsetAsync(bar, 0, 256, stream);
  prep_w1t<<<512, 256, 0, stream>>>(W1, w1t);
  prep_wcomb<<<48, 256, 0, stream>>>(Wh1, Wh2, Wh3, bh1, bh2, bh3, Wf, bfv, wcomb, bcomb);
  gemm_xp1<<<dim3(16, 1024), 256, 0, stream>>>(x, w1t, b1, xp1);
  lstm_persist<<<NWG, 256, 0, stream>>>(U1, W2, U2, b2, xp1, h1buf, h2buf, xp2buf, h2all, bar);
  heads_k<<<NT * NB / 8, 192, 0, stream>>>(h2all, wcomb, bcomb, out);
}

// Round 2
// 16474.387 us; speedup vs baseline: 1.4822x; 1.4822x over previous
//
#include <hip/hip_runtime.h>
#include <hip/hip_bf16.h>
#include <stdint.h>

// Problem dims
#define NB   128
#define NT   1024
#define NF   512
#define NH   512
#define G4   2048   // 4*H
#define NOUT 24
#define NWR  32     // WGs per role
#define NWGS 96     // 3 roles x 32

typedef __attribute__((ext_vector_type(8))) short short8;
typedef __attribute__((ext_vector_type(4))) float f32x4;
typedef unsigned long long u64;

__device__ __forceinline__ float bf2f(short s) {
  union { unsigned u; float f; } v; v.u = ((unsigned)(unsigned short)s) << 16; return v.f;
}
__device__ __forceinline__ short f2bf(float f) {
  union { float f; unsigned u; } v; v.f = f;
  unsigned r = v.u + 0x7FFF + ((v.u >> 16) & 1);   // RNE
  return (short)(r >> 16);
}
// permuted gate-column layout: cp = unitgroup*32 + [i:0-7 | f:8-15 | g:16-23 | o:24-31]
__device__ __forceinline__ int permcol(int cp) {
  int w = cp >> 5, l = cp & 31;
  return ((l >> 3) << 9) | (w << 3) | (l & 7);   // gate*512 + unitgroup*8 + u
}
__device__ __forceinline__ float sigm(float x) { return 1.f / (1.f + __expf(-x)); }
__device__ __forceinline__ float tanh_f(float x) { return 2.f / (1.f + __expf(-2.f * x)) - 1.f; }

__device__ __forceinline__ void spinwait(int* c, int tgt) {
  int it = 0;
  while (__hip_atomic_load(c, __ATOMIC_RELAXED, __HIP_MEMORY_SCOPE_AGENT) < tgt) {
    __builtin_amdgcn_s_sleep(2);
    if (++it > 10000000) break;   // hang guard: fail visibly, don't deadlock
  }
}
__device__ __forceinline__ u64 ld_llc(const void* p) {
  return __hip_atomic_load((u64*)p, __ATOMIC_RELAXED, __HIP_MEMORY_SCOPE_AGENT);
}
__device__ __forceinline__ void st_llc(void* p, u64 v) {
  __hip_atomic_store((u64*)p, v, __ATOMIC_RELAXED, __HIP_MEMORY_SCOPE_AGENT);
}

// ---------------- prep: W1^T (permuted cols, bf16) ----------------
__global__ void prep_w1t(const float* __restrict__ W1, short* __restrict__ w1t) {
  int gid = blockIdx.x * 256 + threadIdx.x;      // 2048*64
  int cp = gid >> 6, kc = gid & 63;
  int orig = permcol(cp);
  const float* sp = W1 + (size_t)(kc * 8) * G4 + orig;
  short8 v;
#pragma unroll
  for (int j = 0; j < 8; ++j) v[j] = f2bf(sp[(size_t)j * G4]);
  *(short8*)&w1t[((size_t)cp << 9) + (kc << 3)] = v;
}

// ---------------- prep: fold 3 heads + final into one [512,24] ----------------
__global__ void prep_wcomb(const float* __restrict__ Wh1, const float* __restrict__ Wh2,
                           const float* __restrict__ Wh3, const float* __restrict__ bh1,
                           const float* __restrict__ bh2, const float* __restrict__ bh3,
                           const float* __restrict__ Wf, const float* __restrict__ bfv,
                           float* __restrict__ wcomb, float* __restrict__ bcomb) {
  int gid = blockIdx.x * 256 + threadIdx.x;
  if (gid < 512 * NOUT) {
    int k = gid / NOUT, o = gid - k * NOUT;
    float a = 0.f;
#pragma unroll
    for (int j = 0; j < 24; ++j) {
      float w = (j < 8) ? Wh1[k * 8 + j] : (j < 16) ? Wh2[k * 8 + (j - 8)] : Wh3[k * 8 + (j - 16)];
      a += w * Wf[j * NOUT + o];
    }
    wcomb[gid] = a;
  }
  if (gid < NOUT) {
    float a = bfv[gid];
#pragma unroll
    for (int j = 0; j < 24; ++j) {
      float bb = (j < 8) ? bh1[j] : (j < 16) ? bh2[j - 8] : bh3[j - 16];
      a += bb * Wf[j * NOUT + gid];
    }
    bcomb[gid] = a;
  }
}

// ---------------- GEMM: xp1[t*128+b][cp] = bf16( x@W1 + b1 ), permuted cols ----------------
__launch_bounds__(256, 2)
__global__ void gemm_xp1(const float* __restrict__ x, const short* __restrict__ w1t,
                         const float* __restrict__ b1, short* __restrict__ xp1) {
  __shared__ __align__(16) short As[128 * 64];
  __shared__ __align__(16) short Bs[128 * 64];
  const int tid = threadIdx.x;
  const int lane = tid & 63, wv = tid >> 6;
  const int wr = wv >> 1, wc = wv & 1;
  const int lc = lane & 15, lq = lane >> 4;
  const int nt = blockIdx.x, tt = blockIdx.y;
  const int n0 = nt << 7;
  f32x4 acc[4][4] = {};

  for (int kt = 0; kt < 8; ++kt) {
    const int k0 = kt << 6;
#pragma unroll
    for (int it = 0; it < 4; ++it) {
      int id = it * 256 + tid;
      int row = id >> 3, ch = id & 7;
      const float* sp = x + ((size_t)row * NT + tt) * NF + k0 + ch * 8;
      f32x4 a0 = *(const f32x4*)sp;
      f32x4 a1 = *(const f32x4*)(sp + 4);
      short8 v;
      v[0] = f2bf(a0[0]); v[1] = f2bf(a0[1]); v[2] = f2bf(a0[2]); v[3] = f2bf(a0[3]);
      v[4] = f2bf(a1[0]); v[5] = f2bf(a1[1]); v[6] = f2bf(a1[2]); v[7] = f2bf(a1[3]);
      *(short8*)&As[(row << 6) + ((ch ^ (row & 7)) << 3)] = v;
      const short* bp = w1t + ((size_t)(n0 + row) << 9) + k0 + ch * 8;
      *(short8*)&Bs[(row << 6) + ((ch ^ (row & 7)) << 3)] = *(const short8*)bp;
    }
    __syncthreads();
#pragma unroll
    for (int ks = 0; ks < 2; ++ks) {
      short8 af[4], bb[4];
#pragma unroll
      for (int i = 0; i < 4; ++i) {
        int ar = wr * 64 + i * 16 + lc;
        int ac = ks * 4 + lq;
        af[i] = *(const short8*)&As[(ar << 6) + ((ac ^ (ar & 7)) << 3)];
        int br = wc * 64 + i * 16 + lc;
        bb[i] = *(const short8*)&Bs[(br << 6) + ((ac ^ (br & 7)) << 3)];
      }
#pragma unroll
      for (int i = 0; i < 4; ++i)
#pragma unroll
        for (int j = 0; j < 4; ++j)
          acc[i][j] = __builtin_amdgcn_mfma_f32_16x16x32_bf16(af[i], bb[j], acc[i][j], 0, 0, 0);
    }
    __syncthreads();
  }
  const size_t m0 = (size_t)tt << 7;
#pragma unroll
  for (int j = 0; j < 4; ++j) {
    int cp = n0 + wc * 64 + j * 16 + lc;
    float bv = b1[permcol(cp)];
#pragma unroll
    for (int i = 0; i < 4; ++i) {
      int rbase = wr * 64 + i * 16 + lq * 4;
#pragma unroll
      for (int r = 0; r < 4; ++r)
        xp1[(m0 + rbase + r) * G4 + cp] = f2bf(acc[i][j][r] + bv);
    }
  }
}

// ---------------- persistent pipelined LSTM, fine-grained LLC (sc1) sync ----------------
// role0: h1[t] = LSTM1(xp1[t], h1[t-1])          32 WGs, 64 gate-cols each
// role1: xp2[t] = h1[t] @ W2 + b2 (frag-packed)  32 WGs
// role2: h2[t] = LSTM2(xp2[t], h2[t-1])          32 WGs
// Exchange buffers depth-4; ALL cross-WG traffic via relaxed agent (sc1) 8B atomics;
// per-step role counters; zero L2 wb/inv in the loop.
__launch_bounds__(512, 1)
__global__ void lstm_persist(const float* __restrict__ U1, const float* __restrict__ W2,
                             const float* __restrict__ U2, const float* __restrict__ b2,
                             const short* __restrict__ xp1,
                             short* __restrict__ h1buf, short* __restrict__ h2buf,
                             short* __restrict__ xp2buf, short* __restrict__ h2all,
                             int* __restrict__ cnt) {
  __shared__ __align__(16) short hs[128 * 256];     // 64 KB K-half staging
  __shared__ __align__(16) short htile[128][20];    // 5 KB h repack (pad 20)
  int* c_h1  = cnt;
  int* c_xp2 = cnt + 2048;
  int* c_h2  = cnt + 4096;

  const int bid = blockIdx.x;
  const int role = bid >> 5;          // 0,1,2
  const int wgc = bid & 31;           // 64 cols (16 h-units) per WG
  const int tid = threadIdx.x;
  const int lane = tid & 63, wv = tid >> 6;
  const int q = wv >> 1, chf = wv & 1;   // row-quarter, col-half
  const int lc = lane & 15, lq = lane >> 4;
  const bool fl = lc >= 8;

  const float* Bmat = (role == 0) ? U1 : (role == 1) ? W2 : U2;

  // one-time: B fragments into registers (2 col-tiles x 16 k-steps) = 128 VGPR
  short8 bfr[2][16];
#pragma unroll
  for (int j = 0; j < 2; ++j) {
    int gcl = j * 16 + lc;
    int orig = ((gcl >> 3) << 9) | ((wgc * 2 + chf) << 3) | (lc & 7);
#pragma unroll
    for (int t16 = 0; t16 < 16; ++t16) {
      const float* up = Bmat + (size_t)(t16 * 32 + lq * 8) * G4 + orig;
      short8 v;
#pragma unroll
      for (int jj = 0; jj < 8; ++jj) v[jj] = f2bf(up[(size_t)jj * G4]);
      bfr[j][t16] = v;
    }
  }
  float bias2[2] = {0.f, 0.f};
  if (role == 1) {
#pragma unroll
    for (int j = 0; j < 2; ++j) {
      int gcl = j * 16 + lc;
      bias2[j] = b2[((gcl >> 3) << 9) | ((wgc * 2 + chf) << 3) | (lc & 7)];
    }
  }
  float cst[2][4] = {};   // c-state (f-lanes)

  for (int t = 0; t < NT; ++t) {
    // ---- fine-grained waits (tid0 spins, WG follows) ----
    if (tid == 0) {
      if (role == 0) {
        if (t > 0)  spinwait(&c_h1[t - 1], NWR);
        if (t >= 4) spinwait(&c_xp2[t - 4], NWR);   // h1 slot reuse guard
      } else if (role == 1) {
        spinwait(&c_h1[t], NWR);
        if (t >= 4) spinwait(&c_h2[t - 4], NWR);    // xp2 slot reuse guard
      } else {
        spinwait(&c_xp2[t], NWR);
        if (t > 0)  spinwait(&c_h2[t - 1], NWR);
      }
    }
    __syncthreads();

    // ---- acc init ----
    f32x4 acc[2][2] = {};
    if (role == 0) {
      const short* xs = xp1 + (size_t)t * NB * G4;
#pragma unroll
      for (int i = 0; i < 2; ++i)
#pragma unroll
        for (int j = 0; j < 2; ++j) {
          int col = (wgc << 6) + (chf << 5) + j * 16 + lc;
#pragma unroll
          for (int r = 0; r < 4; ++r) {
            int row = (q << 5) + i * 16 + lq * 4 + r;
            acc[i][j][r] = bf2f(xs[(size_t)row * G4 + col]);
          }
        }
    } else if (role == 2) {
      const short* xs = xp2buf + (size_t)(t & 3) * NB * G4 +
                        ((((size_t)wgc << 3) + wv) * 64 + lane) * 16;
#pragma unroll
      for (int kk = 0; kk < 4; ++kk) {
        union { u64 u; short s[4]; } pv;
        pv.u = ld_llc(xs + kk * 4);
#pragma unroll
        for (int r = 0; r < 4; ++r) acc[kk >> 1][kk & 1][r] = bf2f(pv.s[r]);
      }
    }

    // ---- recurrent matmul vs staged h ----
    const bool do_mm = (role == 1) || (t > 0);
    if (do_mm) {
      const short* hsrc = (role == 0) ? h1buf + (size_t)((t - 1) & 3) * NB * NH
                        : (role == 1) ? h1buf + (size_t)(t & 3) * NB * NH
                                      : h2buf + (size_t)((t - 1) & 3) * NB * NH;
#pragma unroll
      for (int hf = 0; hf < 2; ++hf) {
        __syncthreads();
#pragma unroll
        for (int it = 0; it < 16; ++it) {
          int c = it * 512 + tid;
          int row = c >> 6, c4 = c & 63;          // 8B chunks, 64 per row-half
          u64 v = ld_llc(hsrc + ((size_t)row << 9) + (hf << 8) + (c4 << 2));
          int sw = (c4 >> 1) ^ (row & 15);
          *(u64*)((char*)hs + row * 512 + sw * 16 + (c4 & 1) * 8) = v;
        }
        __syncthreads();
#pragma unroll
        for (int ks = 0; ks < 8; ++ks) {
          short8 af[2];
#pragma unroll
          for (int i = 0; i < 2; ++i) {
            int row = (q << 5) + i * 16 + lc;
            int ch = ks * 4 + lq;
            af[i] = *(const short8*)((char*)hs + row * 512 + ((ch ^ (row & 15)) << 4));
          }
#pragma unroll
          for (int i = 0; i < 2; ++i)
#pragma unroll
            for (int j = 0; j < 2; ++j)
              acc[i][j] = __builtin_amdgcn_mfma_f32_16x16x32_bf16(af[i], bfr[j][hf * 8 + ks],
                                                                  acc[i][j], 0, 0, 0);
        }
      }
    }

    // ---- produce ----
    if (role == 1) {
      short* xd = xp2buf + (size_t)(t & 3) * NB * G4 +
                  ((((size_t)wgc << 3) + wv) * 64 + lane) * 16;
#pragma unroll
      for (int kk = 0; kk < 4; ++kk) {
        union { u64 u; short s[4]; } pv;
#pragma unroll
        for (int r = 0; r < 4; ++r) pv.s[r] = f2bf(acc[kk >> 1][kk & 1][r] + bias2[kk & 1]);
        st_llc(xd + kk * 4, pv.u);
      }
    } else {
      // gates: acc[i][0] = z_i/z_f ; acc[i][1] = z_g/z_o  (by lane half)
      float hv[2][4];
#pragma unroll
      for (int i = 0; i < 2; ++i)
#pragma unroll
        for (int r = 0; r < 4; ++r) {
          float z0 = acc[i][0][r], z1 = acc[i][1][r];
          float s0 = sigm(z0);                 // i-gate (lc<8) or f-gate (lc>=8)
          float pv = s0 * tanh_f(z1);          // i*tanh(g) on i-lanes
          float ov = sigm(z1);                 // o-gate on f-lanes
          float pr = __shfl_xor(pv, 8);
          if (fl) {
            float cn = s0 * cst[i][r] + pr;
            cst[i][r] = cn;
            hv[i][r] = ov * tanh_f(cn);
          }
        }
      if (fl) {
        int ul = (chf << 3) + (lc - 8);
#pragma unroll
        for (int i = 0; i < 2; ++i)
#pragma unroll
          for (int r = 0; r < 4; ++r)
            htile[(q << 5) + i * 16 + lq * 4 + r][ul] = f2bf(hv[i][r]);
      }
      __syncthreads();
      {
        int row = tid >> 2, c4 = tid & 3;
        u64 v = *(const u64*)&htile[row][c4 * 4];
        short* hb = ((role == 0) ? h1buf : h2buf) + (size_t)(t & 3) * NB * NH;
        st_llc(hb + ((size_t)row << 9) + (wgc << 4) + c4 * 4, v);
        if (role == 2)
          *(u64*)(h2all + ((size_t)t * NB + row) * NH + (wgc << 4) + c4 * 4) = v;
      }
    }

    __syncthreads();   // drains vmcnt: all waves' sc1 stores at LLC before signal
    if (tid == 0) {
      int* cx = (role == 0) ? &c_h1[t] : (role == 1) ? &c_xp2[t] : &c_h2[t];
      __hip_atomic_fetch_add(cx, 1, __ATOMIC_RELAXED, __HIP_MEMORY_SCOPE_AGENT);
    }
  }
}

// ---------------- heads: out = h2 @ Wcomb + bcomb, scattered to [B][T][24] ----------------
__launch_bounds__(192)
__global__ void heads_k(const short* __restrict__ h2all, const float* __restrict__ wcomb,
                        const float* __restrict__ bcomb, float* __restrict__ out) {
  __shared__ float wt[24][516];
  __shared__ float bsh[24];
  const int tid = threadIdx.x;
  for (int id = tid; id < 512 * NOUT; id += 192) {
    int k = id / NOUT, o = id - k * NOUT;
    wt[o][k] = wcomb[id];
  }
  if (tid < NOUT) bsh[tid] = bcomb[tid];
  __syncthreads();
  const int r = tid / NOUT, c = tid - r * NOUT;
  const size_t row = (size_t)blockIdx.x * 8 + r;   // row = t*128 + b
  const short* hp = h2all + row * NH;
  float a = bsh[c];
#pragma unroll 2
  for (int kc = 0; kc < 64; ++kc) {
    short8 hvv = *(const short8*)&hp[kc * 8];
    const float* wp = &wt[c][kc * 8];
#pragma unroll
    for (int e = 0; e < 8; ++e) a += bf2f(hvv[e]) * wp[e];
  }
  const int b = (int)(row & 127), t = (int)(row >> 7);
  out[((size_t)b * NT + t) * NOUT + c] = a;
}

// ---------------- launcher ----------------
extern "C" void kernel_launch(void* const* d_in, const int* in_sizes, int n_in,
                              void* d_out, int out_size, void* d_ws, size_t ws_size,
                              hipStream_t stream) {
  const float* x   = (const float*)d_in[0];
  const float* W1  = (const float*)d_in[1];
  const float* U1  = (const float*)d_in[2];
  const float* b1  = (const float*)d_in[3];
  const float* W2  = (const float*)d_in[4];
  const float* U2  = (const float*)d_in[5];
  const float* b2  = (const float*)d_in[6];
  const float* Wh1 = (const float*)d_in[7];
  const float* bh1 = (const float*)d_in[8];
  const float* Wh2 = (const float*)d_in[9];
  const float* bh2 = (const float*)d_in[10];
  const float* Wh3 = (const float*)d_in[11];
  const float* bh3 = (const float*)d_in[12];
  const float* Wf  = (const float*)d_in[13];
  const float* bfv = (const float*)d_in[14];
  float* out = (float*)d_out;

  char* ws = (char*)d_ws;
  size_t off = 0;
  auto alloc = [&](size_t bytes) { char* p = ws + off; off += (bytes + 255) & ~(size_t)255; return p; };
  int*   cnt    = (int*)  alloc(6144 * 4);                   // 3 counter arrays (2048 ints apart)
  short* xp1    = (short*)alloc((size_t)NT * NB * G4 * 2);   // 536 MB
  short* h2all  = (short*)alloc((size_t)NT * NB * NH * 2);   // 134 MB
  short* h1buf  = (short*)alloc((size_t)4 * NB * NH * 2);    // depth-4
  short* h2buf  = (short*)alloc((size_t)4 * NB * NH * 2);
  short* xp2buf = (short*)alloc((size_t)4 * NB * G4 * 2);
  short* w1t    = (short*)alloc((size_t)G4 * NF * 2);
  float* wcomb  = (float*)alloc(512 * NOUT * 4);
  float* bcomb  = (float*)alloc(256);
  (void)ws_size; (void)in_sizes; (void)n_in; (void)out_size;

  hipMemsetAsync(cnt, 0, 6144 * 4, stream);
  prep_w1t<<<512, 256, 0, stream>>>(W1, w1t);
  prep_wcomb<<<48, 256, 0, stream>>>(Wh1, Wh2, Wh3, bh1, bh2, bh3, Wf, bfv, wcomb, bcomb);
  gemm_xp1<<<dim3(16, 1024), 256, 0, stream>>>(x, w1t, b1, xp1);
  lstm_persist<<<NWGS, 512, 0, stream>>>(U1, W2, U2, b2, xp1, h1buf, h2buf, xp2buf, h2all, cnt);
  heads_k<<<NT * NB / 8, 192, 0, stream>>>(h2all, wcomb, bcomb, out);
}